// Round 10
// baseline (105.175 us; speedup 1.0000x reference)
//
#include <hip/hip_runtime.h>
#include <hip/hip_bf16.h>

#define C_DIM 8192
#define E_DIM 512

using f32x4 = __attribute__((ext_vector_type(4))) float;
using i32x4 = __attribute__((ext_vector_type(4))) int;

__device__ inline void gload_lds16(const void* g, void* l) {
  __builtin_amdgcn_global_load_lds(
      (const __attribute__((address_space(1))) unsigned*)g,
      (__attribute__((address_space(3))) unsigned*)l, 16, 0, 0);
}

__device__ inline unsigned pack_i8x4(float a, float b, float c, float d) {
  unsigned x0 = (unsigned)(__float2int_rn(a * 127.f)) & 255u;
  unsigned x1 = (unsigned)(__float2int_rn(b * 127.f)) & 255u;
  unsigned x2 = (unsigned)(__float2int_rn(c * 127.f)) & 255u;
  unsigned x3 = (unsigned)(__float2int_rn(d * 127.f)) & 255u;
  return x0 | (x1 << 8) | (x2 << 16) | (x3 << 24);
}

// -------- Kernel 1: fused normalize + q colsum + s matvec (soft grid sync) --
// 256 blocks x 256 threads (grid == CU count -> all blocks co-resident, safe
// spin). Phase 1: normalize 32 rows/block (fp32 rows kept in LDS), write i8
// Pi, atomicAdd column partials into q[512]. Soft barrier on qdone. Phase 2:
// s[row] = dot(rows_lds, q) -- no global re-read of the matrix.
__global__ __launch_bounds__(256) void prep_kernel(
    const float* __restrict__ P, unsigned* __restrict__ Pi,
    float* __restrict__ q, unsigned* __restrict__ qdone,
    float* __restrict__ s) {
  __shared__ float rows[32][512];   // 64 KB
  __shared__ float qpart[4][512];   // 8 KB
  __shared__ float qs[512];         // 2 KB
  int wid = threadIdx.x >> 6, lane = threadIdx.x & 63;
  int rbase = blockIdx.x * 32;

  float c0[8];
#pragma unroll
  for (int k = 0; k < 8; ++k) c0[k] = 0.f;

  for (int r8 = 0; r8 < 8; ++r8) {
    int rloc = wid * 8 + r8;
    int row = rbase + rloc;
    const float4* src = (const float4*)(P + (size_t)row * E_DIM);
    float4 v0 = src[lane], v1 = src[lane + 64];
    float ss = v0.x * v0.x + v0.y * v0.y + v0.z * v0.z + v0.w * v0.w +
               v1.x * v1.x + v1.y * v1.y + v1.z * v1.z + v1.w * v1.w;
    for (int m = 32; m; m >>= 1) ss += __shfl_xor(ss, m);
    float inv = 1.0f / fmaxf(sqrtf(ss), 1e-12f);
    v0.x *= inv; v0.y *= inv; v0.z *= inv; v0.w *= inv;
    v1.x *= inv; v1.y *= inv; v1.z *= inv; v1.w *= inv;
    // keep fp32 rows in LDS for phase 2
    *(float4*)&rows[rloc][lane * 4] = v0;
    *(float4*)&rows[rloc][256 + lane * 4] = v1;
    // i8 for the Gram kernel
    Pi[(size_t)row * 128 + lane] = pack_i8x4(v0.x, v0.y, v0.z, v0.w);
    Pi[(size_t)row * 128 + 64 + lane] = pack_i8x4(v1.x, v1.y, v1.z, v1.w);
    // column partial sums (lane owns cols lane*4..+3 and 256+lane*4..+3)
    c0[0] += v0.x; c0[1] += v0.y; c0[2] += v0.z; c0[3] += v0.w;
    c0[4] += v1.x; c0[5] += v1.y; c0[6] += v1.z; c0[7] += v1.w;
  }
#pragma unroll
  for (int k = 0; k < 4; ++k) {
    qpart[wid][lane * 4 + k] = c0[k];
    qpart[wid][256 + lane * 4 + k] = c0[4 + k];
  }
  __syncthreads();
  for (int c = threadIdx.x; c < 512; c += 256) {
    float t = qpart[0][c] + qpart[1][c] + qpart[2][c] + qpart[3][c];
    atomicAdd(&q[c], t);
  }
  __syncthreads();  // all this block's atomics performed (vmcnt drained)

  if (threadIdx.x == 0) {
    __threadfence();
    __hip_atomic_fetch_add(qdone, 1u, __ATOMIC_RELEASE, __HIP_MEMORY_SCOPE_AGENT);
    while (__hip_atomic_load(qdone, __ATOMIC_ACQUIRE, __HIP_MEMORY_SCOPE_AGENT) <
           256u)
      __builtin_amdgcn_s_sleep(2);
  }
  __syncthreads();

  // stage complete q into LDS (device-coherent loads, bypass L1)
  for (int c = threadIdx.x; c < 512; c += 256)
    qs[c] = __hip_atomic_load(&q[c], __ATOMIC_RELAXED, __HIP_MEMORY_SCOPE_AGENT);
  __syncthreads();

  // phase 2: s[row] = dot(rows, q)
  for (int r8 = 0; r8 < 8; ++r8) {
    int rloc = wid * 8 + r8;
    float4 a0 = *(const float4*)&rows[rloc][lane * 4];
    float4 a1 = *(const float4*)&rows[rloc][256 + lane * 4];
    float4 q0 = *(const float4*)&qs[lane * 4];
    float4 q1 = *(const float4*)&qs[256 + lane * 4];
    float d = a0.x * q0.x + a0.y * q0.y + a0.z * q0.z + a0.w * q0.w +
              a1.x * q1.x + a1.y * q1.y + a1.z * q1.z + a1.w * q1.w;
    for (int m = 32; m; m >>= 1) d += __shfl_xor(d, m);
    if (lane == 0) s[rbase + rloc] = d;
  }
}

// ---------------- Kernel 2: fused i8 Gram + exp-entropy partials ------------
// R7 verbatim (best measured): 128x128 upper-triangle tiles, 4 waves, BK=128
// i8 -> 4 K-steps, 16+16 KB LDS, XOR 16B-granule swizzle, slice epilogue.
__global__ __launch_bounds__(256) void gram_kernel(
    const unsigned char* __restrict__ Pi, float* __restrict__ Zp,
    float* __restrict__ Sp) {
  __shared__ unsigned char As[128 * 128];  // 16 KB
  __shared__ unsigned char Bs[128 * 128];  // 16 KB

  // XCD-aware bijective remap (2080 = 8 * 260), then triangular decode
  int b = blockIdx.x;
  int i = (b & 7) * 260 + (b >> 3);
  float bi = 64.5f - sqrtf(64.5f * 64.5f - 2.0f * (float)i);
  int by = (int)bi;
  if (by < 0) by = 0;
  while (64 * (by + 1) - ((by + 1) * by) / 2 <= i) ++by;
  while (64 * by - (by * (by - 1)) / 2 > i) --by;
  int bx = by + (i - (64 * by - (by * (by - 1)) / 2));
  bool diag = (bx == by);

  int tid = threadIdx.x, wid = tid >> 6, lane = tid & 63;
  int wr = wid >> 1, wc = wid & 1;
  int l15 = lane & 15, lh = lane >> 4;

  i32x4 acc[4][4];
#pragma unroll
  for (int m = 0; m < 4; ++m)
#pragma unroll
    for (int n = 0; n < 4; ++n)
      acc[m][n] = (i32x4){0, 0, 0, 0};

  int rs = lane >> 3;               // row within 8-row chunk
  int gsw = (lane & 7) ^ rs;        // pre-swizzled 16B granule (XOR involution)
  const unsigned char* abase = Pi + (size_t)(by * 128) * E_DIM;
  const unsigned char* bbase = Pi + (size_t)(bx * 128) * E_DIM;

  for (int kt = 0; kt < 4; ++kt) {
#pragma unroll
    for (int j = 0; j < 4; ++j) {
      int ci = wid * 4 + j;  // 16 chunks of 8 rows
      int r = ci * 8 + rs;
      gload_lds16(abase + (size_t)r * E_DIM + kt * 128 + gsw * 16,
                  (char*)As + ci * 1024);
      gload_lds16(bbase + (size_t)r * E_DIM + kt * 128 + gsw * 16,
                  (char*)Bs + ci * 1024);
    }
    __syncthreads();

    i32x4 af[4][2], bfr[4][2];
#pragma unroll
    for (int m = 0; m < 4; ++m)
#pragma unroll
      for (int kk = 0; kk < 2; ++kk) {
        int row = wr * 64 + m * 16 + l15;
        int g = (kk * 4 + lh) ^ (row & 7);
        af[m][kk] = *(const i32x4*)(As + row * 128 + g * 16);
      }
#pragma unroll
    for (int n = 0; n < 4; ++n)
#pragma unroll
      for (int kk = 0; kk < 2; ++kk) {
        int row = wc * 64 + n * 16 + l15;
        int g = (kk * 4 + lh) ^ (row & 7);
        bfr[n][kk] = *(const i32x4*)(Bs + row * 128 + g * 16);
      }

#pragma unroll
    for (int kk = 0; kk < 2; ++kk)
#pragma unroll
      for (int m = 0; m < 4; ++m)
#pragma unroll
        for (int n = 0; n < 4; ++n)
          acc[m][n] = __builtin_amdgcn_mfma_i32_16x16x64_i8(
              af[m][kk], bfr[n][kk], acc[m][n], 0, 0, 0);
    if (kt < 3) __syncthreads();
  }

  // epilogue: g = acc/127^2; row partials (reduce over l15) + col partials
  const float invq = 1.0f / 16129.0f;
  float zc[4], sc[4];
#pragma unroll
  for (int n = 0; n < 4; ++n) { zc[n] = 0.f; sc[n] = 0.f; }

  int slotR = bx * 2 + wc;
#pragma unroll
  for (int m = 0; m < 4; ++m) {
#pragma unroll
    for (int reg = 0; reg < 4; ++reg) {
      float z = 0.f, s = 0.f;
#pragma unroll
      for (int n = 0; n < 4; ++n) {
        float g = (float)acc[m][n][reg] * invq;
        float e = __expf(g);
        z += e;
        s += e * g;
        zc[n] += e;
        sc[n] += e * g;
      }
      for (int msk = 8; msk; msk >>= 1) {
        z += __shfl_xor(z, msk);
        s += __shfl_xor(s, msk);
      }
      if (l15 == 0) {
        int rowin = wr * 64 + m * 16 + lh * 4 + reg;
        size_t idx = (size_t)by * 16384 + (size_t)slotR * 128 + rowin;
        Zp[idx] = z;
        Sp[idx] = s;
      }
    }
  }
  if (!diag) {
    int slotC = by * 2 + wr;
#pragma unroll
    for (int n = 0; n < 4; ++n) {
      float z = zc[n], s = sc[n];
      z += __shfl_xor(z, 16); s += __shfl_xor(s, 16);
      z += __shfl_xor(z, 32); s += __shfl_xor(s, 32);
      if (lh == 0) {
        int colin = wc * 64 + n * 16 + l15;
        size_t idx = (size_t)bx * 16384 + (size_t)slotC * 128 + colin;
        Zp[idx] = z;
        Sp[idx] = s;
      }
    }
  }
}

// ------- Kernel 3: fold slices -> per-row entropy; last block finalizes -----
__global__ __launch_bounds__(256) void reduce_kernel(
    const float* __restrict__ Zp, const float* __restrict__ Sp,
    const float* __restrict__ s, float* __restrict__ h_acc,
    unsigned* __restrict__ done, float* __restrict__ out) {
  __shared__ float zbuf[128], sbuf[128];
  __shared__ float red[8];
  __shared__ unsigned lastFlag;
  int rb = blockIdx.x;
  int t = threadIdx.x;
  int lane = t & 63, wid = t >> 6;
  int row = t & 127;
  const float* src = (t >= 128) ? Sp : Zp;
  size_t base = (size_t)rb * 16384 + row;
  float acc = 0.f;
#pragma unroll 8
  for (int sl = 0; sl < 128; ++sl) acc += src[base + (size_t)sl * 128];
  if (t >= 128) sbuf[row] = acc; else zbuf[row] = acc;
  __syncthreads();

  float hp = 0.f;
  if (t < 128) {
    float z = zbuf[t], s2 = sbuf[t];
    hp = logf(z) - s2 / z;
  }
  for (int k = 32; k; k >>= 1) hp += __shfl_xor(hp, k);
  if (lane == 0) red[wid] = hp;
  __syncthreads();
  if (t == 0) {
    float h = red[0] + red[1];
    atomicAdd(h_acc, h);
    __threadfence();
    unsigned old = atomicAdd(done, 1u);
    lastFlag = (old == 63u) ? 1u : 0u;
  }
  __syncthreads();

  if (lastFlag) {
    float m = -3.4e38f;
    for (int i = t; i < C_DIM; i += 256) m = fmaxf(m, s[i]);
    for (int k = 32; k; k >>= 1) m = fmaxf(m, __shfl_xor(m, k));
    if (lane == 0) red[wid] = m;
    __syncthreads();
    m = fmaxf(fmaxf(red[0], red[1]), fmaxf(red[2], red[3]));

    float z = 0.f, sw = 0.f;
    for (int i = t; i < C_DIM; i += 256) {
      float tv = s[i] - m;
      float e = __expf(tv);
      z += e;
      sw += e * tv;
    }
    for (int k = 32; k; k >>= 1) {
      z += __shfl_xor(z, k);
      sw += __shfl_xor(sw, k);
    }
    __syncthreads();
    if (lane == 0) { red[wid] = z; red[4 + wid] = sw; }
    __syncthreads();
    if (t == 0) {
      float zt = red[0] + red[1] + red[2] + red[3];
      float st = red[4] + red[5] + red[6] + red[7];
      float H2 = logf(zt) - st / zt;
      float h = atomicAdd(h_acc, 0.0f);  // coherent read of final sum
      out[0] = h / (float)C_DIM + H2;
    }
  }
}

extern "C" void kernel_launch(void* const* d_in, const int* in_sizes, int n_in,
                              void* d_out, int out_size, void* d_ws, size_t ws_size,
                              hipStream_t stream) {
  const float* P = (const float*)d_in[0];
  float* out = (float*)d_out;

  char* ws = (char*)d_ws;
  unsigned* Pi = (unsigned*)ws;                                 // 4 MB i8
  float* Zp = (float*)(ws + ((size_t)4 << 20));                 // 4 MB
  float* Sp = (float*)(ws + ((size_t)8 << 20));                 // 4 MB
  float* q = (float*)(ws + ((size_t)12 << 20));                 // 2 KB
  float* h_acc = (float*)(ws + ((size_t)12 << 20) + 2048);      // 4 B
  unsigned* done = (unsigned*)(ws + ((size_t)12 << 20) + 2052); // 4 B
  unsigned* qdone = (unsigned*)(ws + ((size_t)12 << 20) + 2056);// 4 B
  float* s = (float*)(ws + ((size_t)12 << 20) + 4096);          // 32 KB

  // zero q + h_acc + done + qdone each launch (deterministic)
  hipMemsetAsync(q, 0, 2060, stream);

  prep_kernel<<<256, 256, 0, stream>>>(P, Pi, q, qdone, s);
  gram_kernel<<<2080, 256, 0, stream>>>((const unsigned char*)Pi, Zp, Sp);
  reduce_kernel<<<64, 256, 0, stream>>>(Zp, Sp, s, h_acc, done, out);
}

// Round 11
// 98.976 us; speedup vs baseline: 1.0626x; 1.0626x over previous
//
#include <hip/hip_runtime.h>
#include <hip/hip_bf16.h>

#define C_DIM 8192
#define E_DIM 512

using f32x4 = __attribute__((ext_vector_type(4))) float;
using i32x4 = __attribute__((ext_vector_type(4))) int;

__device__ inline void gload_lds16(const void* g, void* l) {
  __builtin_amdgcn_global_load_lds(
      (const __attribute__((address_space(1))) unsigned*)g,
      (__attribute__((address_space(3))) unsigned*)l, 16, 0, 0);
}

__device__ inline unsigned pack_bf16(float a, float b) {
  unsigned ua = __float_as_uint(a), ub = __float_as_uint(b);
  ua = (ua + 0x7fffu + ((ua >> 16) & 1u)) >> 16;
  ub = (ub + 0x7fffu + ((ub >> 16) & 1u)) >> 16;
  return ua | (ub << 16);
}

__device__ inline float bf2f(unsigned short u) {
  return __uint_as_float(((unsigned)u) << 16);
}

__device__ inline unsigned pack_i8x4(float a, float b, float c, float d) {
  unsigned x0 = (unsigned)(__float2int_rn(a * 127.f)) & 255u;
  unsigned x1 = (unsigned)(__float2int_rn(b * 127.f)) & 255u;
  unsigned x2 = (unsigned)(__float2int_rn(c * 127.f)) & 255u;
  unsigned x3 = (unsigned)(__float2int_rn(d * 127.f)) & 255u;
  return x0 | (x1 << 8) | (x2 << 16) | (x3 << 24);
}

// ------- Kernel 1: row L2 normalize -> bf16 (for q/s path) + i8 (for Gram) --
__global__ __launch_bounds__(256) void norm_kernel(
    const float* __restrict__ P, unsigned* __restrict__ Pb,
    unsigned* __restrict__ Pi) {
  int wid = threadIdx.x >> 6, lane = threadIdx.x & 63;
  int row = blockIdx.x * 4 + wid;
  const float4* src = (const float4*)(P + (size_t)row * E_DIM);
  float4 v0 = src[lane], v1 = src[lane + 64];
  float ss = v0.x * v0.x + v0.y * v0.y + v0.z * v0.z + v0.w * v0.w +
             v1.x * v1.x + v1.y * v1.y + v1.z * v1.z + v1.w * v1.w;
  for (int m = 32; m; m >>= 1) ss += __shfl_xor(ss, m);
  float inv = 1.0f / fmaxf(sqrtf(ss), 1e-12f);
  v0.x *= inv; v0.y *= inv; v0.z *= inv; v0.w *= inv;
  v1.x *= inv; v1.y *= inv; v1.z *= inv; v1.w *= inv;
  uint2* bd = (uint2*)(Pb + (size_t)row * (E_DIM / 2));
  uint2 b0, b1;
  b0.x = pack_bf16(v0.x, v0.y); b0.y = pack_bf16(v0.z, v0.w);
  b1.x = pack_bf16(v1.x, v1.y); b1.y = pack_bf16(v1.z, v1.w);
  bd[lane] = b0; bd[lane + 64] = b1;
  Pi[(size_t)row * 128 + lane] = pack_i8x4(v0.x, v0.y, v0.z, v0.w);
  Pi[(size_t)row * 128 + 64 + lane] = pack_i8x4(v1.x, v1.y, v1.z, v1.w);
}

// ---------------- Kernel 2: q = column sums of Pb (bf16) --------------------
__global__ __launch_bounds__(256) void qsum_kernel(
    const unsigned short* __restrict__ Pb, float* __restrict__ q) {
  __shared__ float red[4][512];
  int wid = threadIdx.x >> 6, lane = threadIdx.x & 63;
  float a[8];
#pragma unroll
  for (int k = 0; k < 8; ++k) a[k] = 0.f;
  for (int i = 0; i < 32; ++i) {
    int row = blockIdx.x * 128 + wid * 32 + i;
    uint4 v = *(const uint4*)(Pb + (size_t)row * E_DIM + lane * 8);
    a[0] += bf2f((unsigned short)(v.x & 0xffff));
    a[1] += bf2f((unsigned short)(v.x >> 16));
    a[2] += bf2f((unsigned short)(v.y & 0xffff));
    a[3] += bf2f((unsigned short)(v.y >> 16));
    a[4] += bf2f((unsigned short)(v.z & 0xffff));
    a[5] += bf2f((unsigned short)(v.z >> 16));
    a[6] += bf2f((unsigned short)(v.w & 0xffff));
    a[7] += bf2f((unsigned short)(v.w >> 16));
  }
#pragma unroll
  for (int k = 0; k < 8; ++k) red[wid][lane * 8 + k] = a[k];
  __syncthreads();
  for (int c = threadIdx.x; c < 512; c += 256) {
    float t = red[0][c] + red[1][c] + red[2][c] + red[3][c];
    atomicAdd(&q[c], t);
  }
}

// ---------------- Kernel 3: s_j = dot(Pb[j], q) -----------------------------
__global__ __launch_bounds__(256) void ssum_kernel(
    const unsigned short* __restrict__ Pb, const float* __restrict__ q,
    float* __restrict__ s) {
  int wid = threadIdx.x >> 6, lane = threadIdx.x & 63;
  int row = blockIdx.x * 4 + wid;
  uint4 v = *(const uint4*)(Pb + (size_t)row * E_DIM + lane * 8);
  const float4* qv = (const float4*)q;
  float4 q0 = qv[lane * 2], q1 = qv[lane * 2 + 1];
  float d = bf2f((unsigned short)(v.x & 0xffff)) * q0.x +
            bf2f((unsigned short)(v.x >> 16)) * q0.y +
            bf2f((unsigned short)(v.y & 0xffff)) * q0.z +
            bf2f((unsigned short)(v.y >> 16)) * q0.w +
            bf2f((unsigned short)(v.z & 0xffff)) * q1.x +
            bf2f((unsigned short)(v.z >> 16)) * q1.y +
            bf2f((unsigned short)(v.w & 0xffff)) * q1.z +
            bf2f((unsigned short)(v.w >> 16)) * q1.w;
  for (int m = 32; m; m >>= 1) d += __shfl_xor(d, m);
  if (lane == 0) s[row] = d;
}

// ---------------- Kernel 4: i8 Gram, A-in-LDS / B-from-L2, 3 barriers -------
// 128x128 upper-triangle tiles, 4 waves. A tile staged in K-halves (32 KB LDS,
// rows of 256B = 2 kt-regions); B fragments read DIRECTLY from global (Pi is
// 4MB -> L2-resident). No barriers inside compute: 3 per block total.
// XOR swizzle within each 128B kt-subregion (granule ^= row&7), pre-swizzled
// global source + swizzled ds_read (involution both sides). Slice epilogue.
__global__ __launch_bounds__(256) void gram_kernel(
    const unsigned char* __restrict__ Pi, float* __restrict__ Zp,
    float* __restrict__ Sp) {
  __shared__ unsigned char As[128 * 256];  // 32 KB: row stride 256B

  // XCD-aware bijective remap (2080 = 8 * 260), then triangular decode
  int b = blockIdx.x;
  int i = (b & 7) * 260 + (b >> 3);
  float bi = 64.5f - sqrtf(64.5f * 64.5f - 2.0f * (float)i);
  int by = (int)bi;
  if (by < 0) by = 0;
  while (64 * (by + 1) - ((by + 1) * by) / 2 <= i) ++by;
  while (64 * by - (by * (by - 1)) / 2 > i) --by;
  int bx = by + (i - (64 * by - (by * (by - 1)) / 2));
  bool diag = (bx == by);

  int tid = threadIdx.x, wid = tid >> 6, lane = tid & 63;
  int wr = wid >> 1, wc = wid & 1;
  int l15 = lane & 15, lh = lane >> 4;

  i32x4 acc[4][4];
#pragma unroll
  for (int m = 0; m < 4; ++m)
#pragma unroll
    for (int n = 0; n < 4; ++n)
      acc[m][n] = (i32x4){0, 0, 0, 0};

  const unsigned char* abase = Pi + (size_t)(by * 128) * E_DIM;
  // B per-lane row base pointers (fragment: row n*16+l15, 16B chunk lh)
  const unsigned char* bb[4];
#pragma unroll
  for (int n = 0; n < 4; ++n)
    bb[n] = Pi + (size_t)(bx * 128 + wc * 64 + n * 16 + l15) * E_DIM + lh * 16;

  int rs = lane >> 4;  // staging: row within 4-row chunk
  int g = lane & 15;   // staging: granule within 256B half-row

#pragma unroll
  for (int h = 0; h < 2; ++h) {
    if (h) __syncthreads();  // waves done computing on previous half
#pragma unroll
    for (int j = 0; j < 8; ++j) {
      int ci = wid * 8 + j;  // 32 chunks of 4 rows x 256B
      int r = ci * 4 + rs;
      int srcg = (g & 8) | ((g & 7) ^ (r & 7));  // XOR within 128B subregion
      gload_lds16(abase + (size_t)r * E_DIM + h * 256 + srcg * 16,
                  (char*)As + ci * 1024);
    }
    __syncthreads();  // vmcnt drain -> half visible

#pragma unroll
    for (int kt2 = 0; kt2 < 2; ++kt2) {
      int kt = h * 2 + kt2;
      i32x4 bfr[2][4];
#pragma unroll
      for (int kk = 0; kk < 2; ++kk)
#pragma unroll
        for (int n = 0; n < 4; ++n)
          bfr[kk][n] = *(const i32x4*)(bb[n] + kt * 128 + kk * 64);
#pragma unroll
      for (int kk = 0; kk < 2; ++kk) {
        i32x4 af[4];
#pragma unroll
        for (int m = 0; m < 4; ++m) {
          int row = wr * 64 + m * 16 + l15;
          int gsl = (kk * 4 + lh) ^ (l15 & 7);
          af[m] = *(const i32x4*)(As + row * 256 + kt2 * 128 + gsl * 16);
        }
#pragma unroll
        for (int m = 0; m < 4; ++m)
#pragma unroll
          for (int n = 0; n < 4; ++n)
            acc[m][n] = __builtin_amdgcn_mfma_i32_16x16x64_i8(
                af[m], bfr[kk][n], acc[m][n], 0, 0, 0);
      }
    }
  }

  // epilogue: g = acc/127^2; row partials (reduce over l15) + col partials
  const float invq = 1.0f / 16129.0f;
  float zc[4], sc[4];
#pragma unroll
  for (int n = 0; n < 4; ++n) { zc[n] = 0.f; sc[n] = 0.f; }

  int slotR = bx * 2 + wc;
#pragma unroll
  for (int m = 0; m < 4; ++m) {
#pragma unroll
    for (int reg = 0; reg < 4; ++reg) {
      float z = 0.f, s = 0.f;
#pragma unroll
      for (int n = 0; n < 4; ++n) {
        float gv = (float)acc[m][n][reg] * invq;
        float e = __expf(gv);
        z += e;
        s += e * gv;
        zc[n] += e;
        sc[n] += e * gv;
      }
      for (int msk = 8; msk; msk >>= 1) {
        z += __shfl_xor(z, msk);
        s += __shfl_xor(s, msk);
      }
      if (l15 == 0) {
        int rowin = wr * 64 + m * 16 + lh * 4 + reg;
        size_t idx = (size_t)by * 16384 + (size_t)slotR * 128 + rowin;
        Zp[idx] = z;
        Sp[idx] = s;
      }
    }
  }
  if (!diag) {
    int slotC = by * 2 + wr;
#pragma unroll
    for (int n = 0; n < 4; ++n) {
      float z = zc[n], s = sc[n];
      z += __shfl_xor(z, 16); s += __shfl_xor(s, 16);
      z += __shfl_xor(z, 32); s += __shfl_xor(s, 32);
      if (lh == 0) {
        int colin = wc * 64 + n * 16 + l15;
        size_t idx = (size_t)bx * 16384 + (size_t)slotC * 128 + colin;
        Zp[idx] = z;
        Sp[idx] = s;
      }
    }
  }
}

// ------- Kernel 5: fold slices -> per-row entropy; last block finalizes -----
__global__ __launch_bounds__(256) void reduce_kernel(
    const float* __restrict__ Zp, const float* __restrict__ Sp,
    const float* __restrict__ s, float* __restrict__ h_acc,
    unsigned* __restrict__ done, float* __restrict__ out) {
  __shared__ float zbuf[128], sbuf[128];
  __shared__ float red[8];
  __shared__ unsigned lastFlag;
  int rb = blockIdx.x;
  int t = threadIdx.x;
  int lane = t & 63, wid = t >> 6;
  int row = t & 127;
  const float* src = (t >= 128) ? Sp : Zp;
  size_t base = (size_t)rb * 16384 + row;
  float acc = 0.f;
#pragma unroll 8
  for (int sl = 0; sl < 128; ++sl) acc += src[base + (size_t)sl * 128];
  if (t >= 128) sbuf[row] = acc; else zbuf[row] = acc;
  __syncthreads();

  float hp = 0.f;
  if (t < 128) {
    float z = zbuf[t], s2 = sbuf[t];
    hp = logf(z) - s2 / z;
  }
  for (int k = 32; k; k >>= 1) hp += __shfl_xor(hp, k);
  if (lane == 0) red[wid] = hp;
  __syncthreads();
  if (t == 0) {
    float h = red[0] + red[1];
    atomicAdd(h_acc, h);
    __threadfence();
    unsigned old = atomicAdd(done, 1u);
    lastFlag = (old == 63u) ? 1u : 0u;
  }
  __syncthreads();

  if (lastFlag) {
    float m = -3.4e38f;
    for (int i = t; i < C_DIM; i += 256) m = fmaxf(m, s[i]);
    for (int k = 32; k; k >>= 1) m = fmaxf(m, __shfl_xor(m, k));
    if (lane == 0) red[wid] = m;
    __syncthreads();
    m = fmaxf(fmaxf(red[0], red[1]), fmaxf(red[2], red[3]));

    float z = 0.f, sw = 0.f;
    for (int i = t; i < C_DIM; i += 256) {
      float tv = s[i] - m;
      float e = __expf(tv);
      z += e;
      sw += e * tv;
    }
    for (int k = 32; k; k >>= 1) {
      z += __shfl_xor(z, k);
      sw += __shfl_xor(sw, k);
    }
    __syncthreads();
    if (lane == 0) { red[wid] = z; red[4 + wid] = sw; }
    __syncthreads();
    if (t == 0) {
      float zt = red[0] + red[1] + red[2] + red[3];
      float st = red[4] + red[5] + red[6] + red[7];
      float H2 = logf(zt) - st / zt;
      float h = atomicAdd(h_acc, 0.0f);  // coherent read of final sum
      out[0] = h / (float)C_DIM + H2;
    }
  }
}

extern "C" void kernel_launch(void* const* d_in, const int* in_sizes, int n_in,
                              void* d_out, int out_size, void* d_ws, size_t ws_size,
                              hipStream_t stream) {
  const float* P = (const float*)d_in[0];
  float* out = (float*)d_out;

  char* ws = (char*)d_ws;
  unsigned* Pb = (unsigned*)ws;                                  // 8 MB bf16
  unsigned* Pi = (unsigned*)(ws + ((size_t)8 << 20));            // 4 MB i8
  float* Zp = (float*)(ws + ((size_t)12 << 20));                 // 4 MB
  float* Sp = (float*)(ws + ((size_t)16 << 20));                 // 4 MB
  float* q = (float*)(ws + ((size_t)20 << 20));                  // 2 KB
  float* h_acc = (float*)(ws + ((size_t)20 << 20) + 2048);       // 4 B
  unsigned* done = (unsigned*)(ws + ((size_t)20 << 20) + 2052);  // 4 B
  float* s = (float*)(ws + ((size_t)20 << 20) + 4096);           // 32 KB

  // zero q + h_acc + done each launch (deterministic)
  hipMemsetAsync(q, 0, 2056, stream);

  norm_kernel<<<C_DIM / 4, 256, 0, stream>>>(P, Pb, Pi);
  qsum_kernel<<<C_DIM / 128, 256, 0, stream>>>((const unsigned short*)Pb, q);
  ssum_kernel<<<C_DIM / 4, 256, 0, stream>>>((const unsigned short*)Pb, q, s);
  gram_kernel<<<2080, 256, 0, stream>>>((const unsigned char*)Pi, Zp, Sp);
  reduce_kernel<<<64, 256, 0, stream>>>(Zp, Sp, s, h_acc, done, out);
}

// Round 12
// 73.695 us; speedup vs baseline: 1.4272x; 1.3431x over previous
//
#include <hip/hip_runtime.h>
#include <hip/hip_bf16.h>

#define C_DIM 8192
#define E_DIM 512

using f32x4 = __attribute__((ext_vector_type(4))) float;
using i32x4 = __attribute__((ext_vector_type(4))) int;

__device__ inline void gload_lds16(const void* g, void* l) {
  __builtin_amdgcn_global_load_lds(
      (const __attribute__((address_space(1))) unsigned*)g,
      (__attribute__((address_space(3))) unsigned*)l, 16, 0, 0);
}

__device__ inline unsigned pack_bf16(float a, float b) {
  unsigned ua = __float_as_uint(a), ub = __float_as_uint(b);
  ua = (ua + 0x7fffu + ((ua >> 16) & 1u)) >> 16;
  ub = (ub + 0x7fffu + ((ub >> 16) & 1u)) >> 16;
  return ua | (ub << 16);
}

__device__ inline float bf2f(unsigned short u) {
  return __uint_as_float(((unsigned)u) << 16);
}

__device__ inline unsigned pack_i8x4(float a, float b, float c, float d) {
  unsigned x0 = (unsigned)(__float2int_rn(a * 127.f)) & 255u;
  unsigned x1 = (unsigned)(__float2int_rn(b * 127.f)) & 255u;
  unsigned x2 = (unsigned)(__float2int_rn(c * 127.f)) & 255u;
  unsigned x3 = (unsigned)(__float2int_rn(d * 127.f)) & 255u;
  return x0 | (x1 << 8) | (x2 << 16) | (x3 << 24);
}

// ------- Kernel 1: row L2 normalize -> bf16 + i8; block 0 zeroes flags ------
__global__ __launch_bounds__(256) void norm_kernel(
    const float* __restrict__ P, unsigned* __restrict__ Pb,
    unsigned* __restrict__ Pi, float* __restrict__ q,
    float* __restrict__ h_acc, unsigned* __restrict__ done) {
  // replace the memset dispatch: q[512] + h_acc + done zeroed before any
  // consumer runs (qsum/reduce are later, stream-ordered)
  if (blockIdx.x == 0) {
    int t = threadIdx.x;
    q[t] = 0.f;
    q[t + 256] = 0.f;
    if (t == 0) { h_acc[0] = 0.f; done[0] = 0u; }
  }
  int wid = threadIdx.x >> 6, lane = threadIdx.x & 63;
  int row = blockIdx.x * 4 + wid;
  const float4* src = (const float4*)(P + (size_t)row * E_DIM);
  float4 v0 = src[lane], v1 = src[lane + 64];
  float ss = v0.x * v0.x + v0.y * v0.y + v0.z * v0.z + v0.w * v0.w +
             v1.x * v1.x + v1.y * v1.y + v1.z * v1.z + v1.w * v1.w;
  for (int m = 32; m; m >>= 1) ss += __shfl_xor(ss, m);
  float inv = 1.0f / fmaxf(sqrtf(ss), 1e-12f);
  v0.x *= inv; v0.y *= inv; v0.z *= inv; v0.w *= inv;
  v1.x *= inv; v1.y *= inv; v1.z *= inv; v1.w *= inv;
  uint2* bd = (uint2*)(Pb + (size_t)row * (E_DIM / 2));
  uint2 b0, b1;
  b0.x = pack_bf16(v0.x, v0.y); b0.y = pack_bf16(v0.z, v0.w);
  b1.x = pack_bf16(v1.x, v1.y); b1.y = pack_bf16(v1.z, v1.w);
  bd[lane] = b0; bd[lane + 64] = b1;
  Pi[(size_t)row * 128 + lane] = pack_i8x4(v0.x, v0.y, v0.z, v0.w);
  Pi[(size_t)row * 128 + 64 + lane] = pack_i8x4(v1.x, v1.y, v1.z, v1.w);
}

// ---------------- Kernel 2: q = column sums of Pb (bf16) --------------------
__global__ __launch_bounds__(256) void qsum_kernel(
    const unsigned short* __restrict__ Pb, float* __restrict__ q) {
  __shared__ float red[4][512];
  int wid = threadIdx.x >> 6, lane = threadIdx.x & 63;
  float a[8];
#pragma unroll
  for (int k = 0; k < 8; ++k) a[k] = 0.f;
  for (int i = 0; i < 32; ++i) {
    int row = blockIdx.x * 128 + wid * 32 + i;
    uint4 v = *(const uint4*)(Pb + (size_t)row * E_DIM + lane * 8);
    a[0] += bf2f((unsigned short)(v.x & 0xffff));
    a[1] += bf2f((unsigned short)(v.x >> 16));
    a[2] += bf2f((unsigned short)(v.y & 0xffff));
    a[3] += bf2f((unsigned short)(v.y >> 16));
    a[4] += bf2f((unsigned short)(v.z & 0xffff));
    a[5] += bf2f((unsigned short)(v.z >> 16));
    a[6] += bf2f((unsigned short)(v.w & 0xffff));
    a[7] += bf2f((unsigned short)(v.w >> 16));
  }
#pragma unroll
  for (int k = 0; k < 8; ++k) red[wid][lane * 8 + k] = a[k];
  __syncthreads();
  for (int c = threadIdx.x; c < 512; c += 256) {
    float t = red[0][c] + red[1][c] + red[2][c] + red[3][c];
    atomicAdd(&q[c], t);
  }
}

// ---------------- Kernel 3: s_j = dot(Pb[j], q) -----------------------------
__global__ __launch_bounds__(256) void ssum_kernel(
    const unsigned short* __restrict__ Pb, const float* __restrict__ q,
    float* __restrict__ s) {
  int wid = threadIdx.x >> 6, lane = threadIdx.x & 63;
  int row = blockIdx.x * 4 + wid;
  uint4 v = *(const uint4*)(Pb + (size_t)row * E_DIM + lane * 8);
  const float4* qv = (const float4*)q;
  float4 q0 = qv[lane * 2], q1 = qv[lane * 2 + 1];
  float d = bf2f((unsigned short)(v.x & 0xffff)) * q0.x +
            bf2f((unsigned short)(v.x >> 16)) * q0.y +
            bf2f((unsigned short)(v.y & 0xffff)) * q0.z +
            bf2f((unsigned short)(v.y >> 16)) * q0.w +
            bf2f((unsigned short)(v.z & 0xffff)) * q1.x +
            bf2f((unsigned short)(v.z >> 16)) * q1.y +
            bf2f((unsigned short)(v.w & 0xffff)) * q1.z +
            bf2f((unsigned short)(v.w >> 16)) * q1.w;
  for (int m = 32; m; m >>= 1) d += __shfl_xor(d, m);
  if (lane == 0) s[row] = d;
}

// ---------------- Kernel 4: fused i8 Gram + exp-entropy partials ------------
// R7 skeleton with two register-pressure tweaks for 3 waves/SIMD occupancy:
// per-kk operand loads (halves live operand VGPRs) + __launch_bounds__(256,3).
__global__ __launch_bounds__(256, 3) void gram_kernel(
    const unsigned char* __restrict__ Pi, float* __restrict__ Zp,
    float* __restrict__ Sp) {
  __shared__ unsigned char As[128 * 128];  // 16 KB
  __shared__ unsigned char Bs[128 * 128];  // 16 KB

  // XCD-aware bijective remap (2080 = 8 * 260), then triangular decode
  int b = blockIdx.x;
  int i = (b & 7) * 260 + (b >> 3);
  float bi = 64.5f - sqrtf(64.5f * 64.5f - 2.0f * (float)i);
  int by = (int)bi;
  if (by < 0) by = 0;
  while (64 * (by + 1) - ((by + 1) * by) / 2 <= i) ++by;
  while (64 * by - (by * (by - 1)) / 2 > i) --by;
  int bx = by + (i - (64 * by - (by * (by - 1)) / 2));
  bool diag = (bx == by);

  int tid = threadIdx.x, wid = tid >> 6, lane = tid & 63;
  int wr = wid >> 1, wc = wid & 1;
  int l15 = lane & 15, lh = lane >> 4;

  i32x4 acc[4][4];
#pragma unroll
  for (int m = 0; m < 4; ++m)
#pragma unroll
    for (int n = 0; n < 4; ++n)
      acc[m][n] = (i32x4){0, 0, 0, 0};

  int rs = lane >> 3;               // row within 8-row chunk
  int gsw = (lane & 7) ^ rs;        // pre-swizzled 16B granule (XOR involution)
  const unsigned char* abase = Pi + (size_t)(by * 128) * E_DIM;
  const unsigned char* bbase = Pi + (size_t)(bx * 128) * E_DIM;

  for (int kt = 0; kt < 4; ++kt) {
#pragma unroll
    for (int j = 0; j < 4; ++j) {
      int ci = wid * 4 + j;  // 16 chunks of 8 rows
      int r = ci * 8 + rs;
      gload_lds16(abase + (size_t)r * E_DIM + kt * 128 + gsw * 16,
                  (char*)As + ci * 1024);
      gload_lds16(bbase + (size_t)r * E_DIM + kt * 128 + gsw * 16,
                  (char*)Bs + ci * 1024);
    }
    __syncthreads();

#pragma unroll
    for (int kk = 0; kk < 2; ++kk) {
      i32x4 af[4], bfr[4];
#pragma unroll
      for (int m = 0; m < 4; ++m) {
        int row = wr * 64 + m * 16 + l15;
        int g = (kk * 4 + lh) ^ (row & 7);
        af[m] = *(const i32x4*)(As + row * 128 + g * 16);
      }
#pragma unroll
      for (int n = 0; n < 4; ++n) {
        int row = wc * 64 + n * 16 + l15;
        int g = (kk * 4 + lh) ^ (row & 7);
        bfr[n] = *(const i32x4*)(Bs + row * 128 + g * 16);
      }
#pragma unroll
      for (int m = 0; m < 4; ++m)
#pragma unroll
        for (int n = 0; n < 4; ++n)
          acc[m][n] = __builtin_amdgcn_mfma_i32_16x16x64_i8(
              af[m], bfr[n], acc[m][n], 0, 0, 0);
    }
    if (kt < 3) __syncthreads();
  }

  // epilogue: g = acc/127^2; row partials (reduce over l15) + col partials
  const float invq = 1.0f / 16129.0f;
  float zc[4], sc[4];
#pragma unroll
  for (int n = 0; n < 4; ++n) { zc[n] = 0.f; sc[n] = 0.f; }

  int slotR = bx * 2 + wc;
#pragma unroll
  for (int m = 0; m < 4; ++m) {
#pragma unroll
    for (int reg = 0; reg < 4; ++reg) {
      float z = 0.f, s = 0.f;
#pragma unroll
      for (int n = 0; n < 4; ++n) {
        float g = (float)acc[m][n][reg] * invq;
        float e = __expf(g);
        z += e;
        s += e * g;
        zc[n] += e;
        sc[n] += e * g;
      }
      for (int msk = 8; msk; msk >>= 1) {
        z += __shfl_xor(z, msk);
        s += __shfl_xor(s, msk);
      }
      if (l15 == 0) {
        int rowin = wr * 64 + m * 16 + lh * 4 + reg;
        size_t idx = (size_t)by * 16384 + (size_t)slotR * 128 + rowin;
        Zp[idx] = z;
        Sp[idx] = s;
      }
    }
  }
  if (!diag) {
    int slotC = by * 2 + wr;
#pragma unroll
    for (int n = 0; n < 4; ++n) {
      float z = zc[n], s = sc[n];
      z += __shfl_xor(z, 16); s += __shfl_xor(s, 16);
      z += __shfl_xor(z, 32); s += __shfl_xor(s, 32);
      if (lh == 0) {
        int colin = wc * 64 + n * 16 + l15;
        size_t idx = (size_t)bx * 16384 + (size_t)slotC * 128 + colin;
        Zp[idx] = z;
        Sp[idx] = s;
      }
    }
  }
}

// ------- Kernel 5: fold slices -> per-row entropy; last block finalizes -----
__global__ __launch_bounds__(256) void reduce_kernel(
    const float* __restrict__ Zp, const float* __restrict__ Sp,
    const float* __restrict__ s, float* __restrict__ h_acc,
    unsigned* __restrict__ done, float* __restrict__ out) {
  __shared__ float zbuf[128], sbuf[128];
  __shared__ float red[8];
  __shared__ unsigned lastFlag;
  int rb = blockIdx.x;
  int t = threadIdx.x;
  int lane = t & 63, wid = t >> 6;
  int row = t & 127;
  const float* src = (t >= 128) ? Sp : Zp;
  size_t base = (size_t)rb * 16384 + row;
  float acc = 0.f;
#pragma unroll 8
  for (int sl = 0; sl < 128; ++sl) acc += src[base + (size_t)sl * 128];
  if (t >= 128) sbuf[row] = acc; else zbuf[row] = acc;
  __syncthreads();

  float hp = 0.f;
  if (t < 128) {
    float z = zbuf[t], s2 = sbuf[t];
    hp = logf(z) - s2 / z;
  }
  for (int k = 32; k; k >>= 1) hp += __shfl_xor(hp, k);
  if (lane == 0) red[wid] = hp;
  __syncthreads();
  if (t == 0) {
    float h = red[0] + red[1];
    atomicAdd(h_acc, h);
    __threadfence();
    unsigned old = atomicAdd(done, 1u);
    lastFlag = (old == 63u) ? 1u : 0u;
  }
  __syncthreads();

  if (lastFlag) {
    float m = -3.4e38f;
    for (int i = t; i < C_DIM; i += 256) m = fmaxf(m, s[i]);
    for (int k = 32; k; k >>= 1) m = fmaxf(m, __shfl_xor(m, k));
    if (lane == 0) red[wid] = m;
    __syncthreads();
    m = fmaxf(fmaxf(red[0], red[1]), fmaxf(red[2], red[3]));

    float z = 0.f, sw = 0.f;
    for (int i = t; i < C_DIM; i += 256) {
      float tv = s[i] - m;
      float e = __expf(tv);
      z += e;
      sw += e * tv;
    }
    for (int k = 32; k; k >>= 1) {
      z += __shfl_xor(z, k);
      sw += __shfl_xor(sw, k);
    }
    __syncthreads();
    if (lane == 0) { red[wid] = z; red[4 + wid] = sw; }
    __syncthreads();
    if (t == 0) {
      float zt = red[0] + red[1] + red[2] + red[3];
      float st = red[4] + red[5] + red[6] + red[7];
      float H2 = logf(zt) - st / zt;
      float h = atomicAdd(h_acc, 0.0f);  // coherent read of final sum
      out[0] = h / (float)C_DIM + H2;
    }
  }
}

extern "C" void kernel_launch(void* const* d_in, const int* in_sizes, int n_in,
                              void* d_out, int out_size, void* d_ws, size_t ws_size,
                              hipStream_t stream) {
  const float* P = (const float*)d_in[0];
  float* out = (float*)d_out;

  char* ws = (char*)d_ws;
  unsigned* Pb = (unsigned*)ws;                                  // 8 MB bf16
  unsigned* Pi = (unsigned*)(ws + ((size_t)8 << 20));            // 4 MB i8
  float* Zp = (float*)(ws + ((size_t)12 << 20));                 // 4 MB
  float* Sp = (float*)(ws + ((size_t)16 << 20));                 // 4 MB
  float* q = (float*)(ws + ((size_t)20 << 20));                  // 2 KB
  float* h_acc = (float*)(ws + ((size_t)20 << 20) + 2048);       // 4 B
  unsigned* done = (unsigned*)(ws + ((size_t)20 << 20) + 2052);  // 4 B
  float* s = (float*)(ws + ((size_t)20 << 20) + 4096);           // 32 KB

  norm_kernel<<<C_DIM / 4, 256, 0, stream>>>(P, Pb, Pi, q, h_acc, done);
  qsum_kernel<<<C_DIM / 128, 256, 0, stream>>>((const unsigned short*)Pb, q);
  ssum_kernel<<<C_DIM / 4, 256, 0, stream>>>((const unsigned short*)Pb, q, s);
  gram_kernel<<<2080, 256, 0, stream>>>((const unsigned char*)Pi, Zp, Sp);
  reduce_kernel<<<64, 256, 0, stream>>>(Zp, Sp, s, h_acc, done, out);
}